// Round 3
// baseline (171.113 us; speedup 1.0000x reference)
//
#include <hip/hip_runtime.h>
#include <math.h>

#define F 8
#define C 4096
#define NOFF 28             // i<j factor pairs (diag G_ii is closed-form)
#define NPAIR 36            // i<=j pairs
#define EPSF 1e-8f

#define QCHUNK 128          // q per block, read via uniform scalar loads (SGPR)
#define NCHUNK (C / QCHUNK) // 32
#define PBLK 256            // p per block, one per thread
#define NPB (C / PBLK)      // 16
#define NBLK (NPB * NCHUNK) // 512 blocks = 2/CU
#define NWAVE (NBLK * 4)    // per-wave gram partial sets

// ws layout (all plain stores, no init needed):
//   part [NCHUNK][F][C]  row-sum partials (4 MB)
//   gpart[NWAVE][NOFF]   per-wave off-diag Gram partials (224 KB)
//   spart[NSB][60]       per-block D/T/Q/T0 partials (15 KB)
#define WS_PART  (NCHUNK * F * C)
#define N_GPART  (NWAVE * NOFF)
#define NSB      64

__device__ __forceinline__ float wave_reduce(float v) {
    #pragma unroll
    for (int off = 32; off > 0; off >>= 1) v += __shfl_down(v, off, 64);
    return v;
}

// Each lane owns one p. q values are BLOCK-UNIFORM global reads -> the
// compiler scalarizes them to s_load into SGPRs (SMEM pipe, scalar cache),
// so the inner loop is pure VALU: 32 sub + 24 add + 112 FMA per 4 q.
// No LDS, no barriers, no atomics.
__global__ __launch_bounds__(256) void pair_kernel(const float* __restrict__ x,
                                                   float* __restrict__ part,
                                                   float* __restrict__ gpart) {
    const int tid  = threadIdx.x;
    const int lane = tid & 63;
    const int wave = tid >> 6;
    const int pb   = blockIdx.x & (NPB - 1);
    const int qc   = blockIdx.x >> 4;                // NPB == 16
    const int p    = pb * PBLK + tid;

    float xp[F];
    #pragma unroll
    for (int f = 0; f < F; ++f) xp[f] = x[f * C + p];

    float g[NOFF];
    #pragma unroll
    for (int k = 0; k < NOFF; ++k) g[k] = 0.0f;
    float rs[F];
    #pragma unroll
    for (int f = 0; f < F; ++f) rs[f] = 0.0f;

    const float4* xq = (const float4*)x;

    #pragma unroll 4
    for (int g4 = 0; g4 < QCHUNK / 4; ++g4) {
        float a0[F], a1[F], a2[F], a3[F];
        #pragma unroll
        for (int f = 0; f < F; ++f) {
            // block-uniform address -> s_load_dwordx4 (SGPR broadcast)
            const float4 v = xq[f * (C / 4) + qc * (QCHUNK / 4) + g4];
            a0[f] = __builtin_fabsf(v.x - xp[f]);
            a1[f] = __builtin_fabsf(v.y - xp[f]);
            a2[f] = __builtin_fabsf(v.z - xp[f]);
            a3[f] = __builtin_fabsf(v.w - xp[f]);
            rs[f] += (a0[f] + a1[f]) + (a2[f] + a3[f]);
        }
        int k = 0;
        #pragma unroll
        for (int i = 0; i < F; ++i) {
            #pragma unroll
            for (int j = i + 1; j < F; ++j) {
                g[k] = __builtin_fmaf(a0[i], a0[j], g[k]);
                g[k] = __builtin_fmaf(a1[i], a1[j], g[k]);
                g[k] = __builtin_fmaf(a2[i], a2[j], g[k]);
                g[k] = __builtin_fmaf(a3[i], a3[j], g[k]);
                ++k;
            }
        }
    }

    // row-sum partials: plain coalesced stores
    #pragma unroll
    for (int f = 0; f < F; ++f) part[(qc * F + f) * C + p] = rs[f];

    // per-wave gram partials: wave-reduce, lane 0 stores 28 contiguous floats
    #pragma unroll
    for (int k = 0; k < NOFF; ++k) g[k] = wave_reduce(g[k]);
    if (lane == 0) {
        float* gp = gpart + (blockIdx.x * 4 + wave) * NOFF;
        #pragma unroll
        for (int k = 0; k < NOFF; ++k) gp[k] = g[k];
    }
}

// One thread per p (64 blocks x 64 lanes): reduce the 32 q-chunk partials to
// full s_f(p), then form D/T plus the x-moments Q/T0 for closed-form G_ii.
__global__ __launch_bounds__(64) void sred_kernel(const float* __restrict__ x,
                                                  const float* __restrict__ part,
                                                  float* __restrict__ spart) {
    const int lane = threadIdx.x;
    const int p    = blockIdx.x * 64 + lane;

    float sv[F];
    #pragma unroll
    for (int f = 0; f < F; ++f) sv[f] = 0.0f;
    #pragma unroll 2
    for (int qc = 0; qc < NCHUNK; ++qc) {
        #pragma unroll
        for (int f = 0; f < F; ++f) sv[f] += part[(qc * F + f) * C + p];
    }

    float xv[F];
    #pragma unroll
    for (int f = 0; f < F; ++f) xv[f] = x[f * C + p];

    float vals[60];              // D[36] | T[8] | Q[8] | T0[8]
    int k = 0;
    #pragma unroll
    for (int i = 0; i < F; ++i)
        #pragma unroll
        for (int j = i; j < F; ++j) { vals[k] = sv[i] * sv[j]; ++k; }
    #pragma unroll
    for (int f = 0; f < F; ++f) vals[36 + f] = sv[f];
    #pragma unroll
    for (int f = 0; f < F; ++f) vals[44 + f] = xv[f] * xv[f];
    #pragma unroll
    for (int f = 0; f < F; ++f) vals[52 + f] = xv[f];

    #pragma unroll
    for (int t = 0; t < 60; ++t) vals[t] = wave_reduce(vals[t]);
    if (lane == 0) {
        float* sp = spart + blockIdx.x * 60;
        #pragma unroll
        for (int t = 0; t < 60; ++t) sp[t] = vals[t];
    }
}

__global__ __launch_bounds__(256) void finish_kernel(const float* __restrict__ gpart,
                                                     const float* __restrict__ spart,
                                                     float* __restrict__ out) {
    // A: G_offdiag[0,28) | D[28,64) | T[64,72) | Q[72,80) | T0[80,88)
    __shared__ float A[96];
    __shared__ float redG[NOFF][8];
    const int tid = threadIdx.x;

    if (tid < NOFF * 8) {
        const int k = tid >> 3, c = tid & 7;
        float s = 0.0f;
        for (int b = c; b < NWAVE; b += 8) s += gpart[b * NOFF + k];
        redG[k][c] = s;
    }
    if (tid >= 64 && tid < 124) {
        const int t = tid - 64;
        float s = 0.0f;
        for (int b = 0; b < NSB; ++b) s += spart[b * 60 + t];
        A[28 + t] = s;
    }
    __syncthreads();
    if (tid < NOFF) {
        float s = 0.0f;
        #pragma unroll
        for (int c = 0; c < 8; ++c) s += redG[tid][c];
        A[tid] = s;
    }
    __syncthreads();
    if (tid == 0) {
        const float invC  = 1.0f / (float)C;   // 2^-12, exact
        const float invC2 = invC * invC;       // 2^-24, exact
        float dcov[NPAIR], diag[F];
        int k = 0, ko = 0;
        for (int i = 0; i < F; ++i)
            for (int j = i; j < F; ++j) {
                float G;
                if (i == j) {
                    // closed form: sum_pq (x_p - x_q)^2 = 2C*sum(x^2) - 2*(sum x)^2
                    G = 2.0f * (float)C * A[72 + i] - 2.0f * A[80 + i] * A[80 + i];
                } else {
                    G = A[ko]; ++ko;
                }
                // S_ij = G/C^2 - 2 D/C^3 + T_i T_j / C^4
                const float S = G * invC2 - 2.0f * A[28 + k] * invC2 * invC
                              + (A[64 + i] * invC2) * (A[64 + j] * invC2);
                const float dc = __builtin_amdgcn_sqrtf(fmaxf(S, 0.0f) + EPSF);
                dcov[k] = dc;
                if (i == j) diag[i] = dc;
                ++k;
            }
        float cor = 0.0f;
        k = 0;
        for (int i = 0; i < F; ++i)
            for (int j = i; j < F; ++j) {
                if (j > i)
                    cor += dcov[k] * __builtin_amdgcn_rcpf(
                               __builtin_amdgcn_sqrtf(diag[i] * diag[j] + EPSF));
                ++k;
            }
        out[0] = cor;
    }
}

extern "C" void kernel_launch(void* const* d_in, const int* in_sizes, int n_in,
                              void* d_out, int out_size, void* d_ws, size_t ws_size,
                              hipStream_t stream) {
    const float* x = (const float*)d_in[0];
    float* part  = (float*)d_ws;
    float* gpart = part + WS_PART;
    float* spart = gpart + N_GPART;
    float* out   = (float*)d_out;

    hipLaunchKernelGGL(pair_kernel,   dim3(NBLK), dim3(256), 0, stream, x, part, gpart);
    hipLaunchKernelGGL(sred_kernel,   dim3(NSB),  dim3(64),  0, stream, x, part, spart);
    hipLaunchKernelGGL(finish_kernel, dim3(1),    dim3(256), 0, stream, gpart, spart, out);
}

// Round 4
// 94.228 us; speedup vs baseline: 1.8159x; 1.8159x over previous
//
#include <hip/hip_runtime.h>
#include <math.h>

#define F 8
#define C 4096
#define NOFF 28             // i<j factor pairs (diag G_ii is closed-form)
#define NPAIR 36            // i<=j pairs
#define EPSF 1e-8f

#define QCHUNK 128          // q per block, wave-uniform scalar loads (SGPR)
#define NCHUNK (C / QCHUNK) // 32
#define PBLK 256            // p per block, one per thread
#define NPB (C / PBLK)      // 16
#define NBLK (NPB * NCHUNK) // 512 blocks

#define NSB 16              // sred blocks (4096 threads total, 1 per p)

// ws layout (all plain stores, no init needed):
//   part [NCHUNK][F][C]   row-sum partials (4 MB)
//   gpart[NBLK][NOFF]     per-block off-diag Gram partials (56 KB)
//   sout [NSB][88]        per-sred-block: D[36]|T[8]|Q[8]|T0[8] then G[28]
#define WS_PART (NCHUNK * F * C)
#define WS_GP   (NBLK * NOFF)

__device__ __forceinline__ float wave_reduce(float v) {
    #pragma unroll
    for (int off = 32; off > 0; off >>= 1) v += __shfl_down(v, off, 64);
    return v;
}

// Each lane owns one p. q values are block-uniform global reads -> scalarized
// to s_load_dwordx4 (SMEM pipe). Software-pipelined: next iteration's 8
// scalar loads are in flight while the current 168-VALU block executes.
__global__ __launch_bounds__(256) void pair_kernel(const float* __restrict__ x,
                                                   float* __restrict__ part,
                                                   float* __restrict__ gpart) {
    __shared__ float red[4][NOFF];
    const int tid  = threadIdx.x;
    const int lane = tid & 63;
    const int wave = tid >> 6;
    const int pb   = blockIdx.x & (NPB - 1);
    const int qc   = blockIdx.x >> 4;                // NPB == 16
    const int p    = pb * PBLK + tid;

    float xp[F];
    #pragma unroll
    for (int f = 0; f < F; ++f) xp[f] = x[f * C + p];

    float g[NOFF];
    #pragma unroll
    for (int k = 0; k < NOFF; ++k) g[k] = 0.0f;
    float rs[F];
    #pragma unroll
    for (int f = 0; f < F; ++f) rs[f] = 0.0f;

    const float4* xqb = (const float4*)x + qc * (QCHUNK / 4);

    float4 cur[F];
    #pragma unroll
    for (int f = 0; f < F; ++f) cur[f] = xqb[f * (C / 4)];

    #pragma unroll 1
    for (int g4 = 0; g4 < QCHUNK / 4; ++g4) {
        // prefetch next octet (wraps to 0 on last iter; harmless reload)
        const int nidx = (g4 + 1) & (QCHUNK / 4 - 1);
        float4 nxt[F];
        #pragma unroll
        for (int f = 0; f < F; ++f) nxt[f] = xqb[f * (C / 4) + nidx];

        float a0[F], a1[F], a2[F], a3[F];
        #pragma unroll
        for (int f = 0; f < F; ++f) {
            a0[f] = __builtin_fabsf(cur[f].x - xp[f]);
            a1[f] = __builtin_fabsf(cur[f].y - xp[f]);
            a2[f] = __builtin_fabsf(cur[f].z - xp[f]);
            a3[f] = __builtin_fabsf(cur[f].w - xp[f]);
            rs[f] += (a0[f] + a1[f]) + (a2[f] + a3[f]);
        }
        int k = 0;
        #pragma unroll
        for (int i = 0; i < F; ++i) {
            #pragma unroll
            for (int j = i + 1; j < F; ++j) {
                g[k] = __builtin_fmaf(a0[i], a0[j], g[k]);
                g[k] = __builtin_fmaf(a1[i], a1[j], g[k]);
                g[k] = __builtin_fmaf(a2[i], a2[j], g[k]);
                g[k] = __builtin_fmaf(a3[i], a3[j], g[k]);
                ++k;
            }
        }
        #pragma unroll
        for (int f = 0; f < F; ++f) cur[f] = nxt[f];
    }

    // row-sum partials: plain coalesced stores
    #pragma unroll
    for (int f = 0; f < F; ++f) part[(qc * F + f) * C + p] = rs[f];

    // per-BLOCK gram partials: wave reduce -> LDS -> 28 plain stores
    #pragma unroll
    for (int k = 0; k < NOFF; ++k) g[k] = wave_reduce(g[k]);
    if (lane == 0) {
        #pragma unroll
        for (int k = 0; k < NOFF; ++k) red[wave][k] = g[k];
    }
    __syncthreads();
    if (tid < NOFF)
        gpart[blockIdx.x * NOFF + tid] =
            red[0][tid] + red[1][tid] + red[2][tid] + red[3][tid];
}

// 16 blocks x 256 threads, one thread per p: reduce the 32 q-chunk row-sum
// partials -> s_f(p), form D/T and x-moments Q/T0; ALSO reduce this block's
// 32-block slice of the gram partials with 8-way parallel unrolled loads.
__global__ __launch_bounds__(256) void sred_kernel(const float* __restrict__ x,
                                                   const float* __restrict__ part,
                                                   const float* __restrict__ gpart,
                                                   float* __restrict__ sout) {
    __shared__ float red[4][60];
    __shared__ float gred[NOFF][8];
    const int tid  = threadIdx.x;
    const int lane = tid & 63;
    const int wave = tid >> 6;
    const int p    = blockIdx.x * 256 + tid;

    float sv[F];
    #pragma unroll
    for (int f = 0; f < F; ++f) sv[f] = 0.0f;
    #pragma unroll 4
    for (int qc = 0; qc < NCHUNK; ++qc) {
        #pragma unroll
        for (int f = 0; f < F; ++f) sv[f] += part[(qc * F + f) * C + p];
    }

    float xv[F];
    #pragma unroll
    for (int f = 0; f < F; ++f) xv[f] = x[f * C + p];

    float vals[60];              // D[36] | T[8] | Q[8] | T0[8]
    int k = 0;
    #pragma unroll
    for (int i = 0; i < F; ++i)
        #pragma unroll
        for (int j = i; j < F; ++j) { vals[k] = sv[i] * sv[j]; ++k; }
    #pragma unroll
    for (int f = 0; f < F; ++f) vals[36 + f] = sv[f];
    #pragma unroll
    for (int f = 0; f < F; ++f) vals[44 + f] = xv[f] * xv[f];
    #pragma unroll
    for (int f = 0; f < F; ++f) vals[52 + f] = xv[f];

    #pragma unroll
    for (int t = 0; t < 60; ++t) vals[t] = wave_reduce(vals[t]);
    if (lane == 0) {
        #pragma unroll
        for (int t = 0; t < 60; ++t) red[wave][t] = vals[t];
    }

    // gram partial slice: 224 threads, each sums 4 of this block's 32 rows
    if (tid < NOFF * 8) {
        const int gk = tid >> 3, c = tid & 7;
        float s = 0.0f;
        #pragma unroll
        for (int it = 0; it < 4; ++it)
            s += gpart[(blockIdx.x * 32 + c + 8 * it) * NOFF + gk];
        gred[gk][c] = s;
    }
    __syncthreads();
    if (tid < 60)
        sout[blockIdx.x * 88 + tid] =
            red[0][tid] + red[1][tid] + red[2][tid] + red[3][tid];
    if (tid >= 64 && tid < 64 + NOFF) {
        const int gk = tid - 64;
        float s = 0.0f;
        #pragma unroll
        for (int c = 0; c < 8; ++c) s += gred[gk][c];
        sout[blockIdx.x * 88 + 60 + gk] = s;
    }
}

__global__ __launch_bounds__(128) void finish_kernel(const float* __restrict__ sout,
                                                     float* __restrict__ out) {
    // A: D[0,36) | T[36,44) | Q[44,52) | T0[52,60) | G_offdiag[60,88)
    __shared__ float A[88];
    const int tid = threadIdx.x;
    if (tid < 88) {
        float s = 0.0f;
        #pragma unroll
        for (int b = 0; b < NSB; ++b) s += sout[b * 88 + tid];
        A[tid] = s;
    }
    __syncthreads();
    if (tid == 0) {
        const float invC  = 1.0f / (float)C;   // 2^-12, exact
        const float invC2 = invC * invC;       // 2^-24, exact
        float dcov[NPAIR], diag[F];
        int k = 0, ko = 0;
        for (int i = 0; i < F; ++i)
            for (int j = i; j < F; ++j) {
                float G;
                if (i == j) {
                    // closed form: sum_pq (x_p - x_q)^2 = 2C*sum(x^2) - 2*(sum x)^2
                    G = 2.0f * (float)C * A[44 + i] - 2.0f * A[52 + i] * A[52 + i];
                } else {
                    G = A[60 + ko]; ++ko;
                }
                // S_ij = G/C^2 - 2 D/C^3 + T_i T_j / C^4
                const float S = G * invC2 - 2.0f * A[k] * invC2 * invC
                              + (A[36 + i] * invC2) * (A[36 + j] * invC2);
                const float dc = __builtin_amdgcn_sqrtf(fmaxf(S, 0.0f) + EPSF);
                dcov[k] = dc;
                if (i == j) diag[i] = dc;
                ++k;
            }
        float cor = 0.0f;
        k = 0;
        for (int i = 0; i < F; ++i)
            for (int j = i; j < F; ++j) {
                if (j > i)
                    cor += dcov[k] * __builtin_amdgcn_rcpf(
                               __builtin_amdgcn_sqrtf(diag[i] * diag[j] + EPSF));
                ++k;
            }
        out[0] = cor;
    }
}

extern "C" void kernel_launch(void* const* d_in, const int* in_sizes, int n_in,
                              void* d_out, int out_size, void* d_ws, size_t ws_size,
                              hipStream_t stream) {
    const float* x = (const float*)d_in[0];
    float* part  = (float*)d_ws;
    float* gpart = part + WS_PART;
    float* sout  = gpart + WS_GP;
    float* out   = (float*)d_out;

    hipLaunchKernelGGL(pair_kernel,   dim3(NBLK), dim3(256), 0, stream, x, part, gpart);
    hipLaunchKernelGGL(sred_kernel,   dim3(NSB),  dim3(256), 0, stream, x, part, gpart, sout);
    hipLaunchKernelGGL(finish_kernel, dim3(1),    dim3(128), 0, stream, sout, out);
}